// Round 7
// baseline (7995.927 us; speedup 1.0000x reference)
//
#include <hip/hip_runtime.h>

#define BB 64
#define TT 256
#define DD 512
#define HH 1024
#define NCLS 1000

#define NB   256       // persistent blocks (1/CU via LDS)
#define L0B  128       // blocks [0,128): layer0; [128,256): layer1
#define COLS 8         // h-columns per block
#define HSZ  (BB * HH) // elements per h snapshot (parity double-buffered)
#define CHK0 48        // K0/32 chunks (512 x + 1024 h)
#define CHK1 64        // K1/32 chunks (1024 h0 + 1024 h1)
#define TS0  (CHK0 * 512)
#define TS1  (CHK1 * 512)
// LDS: packed W frags (2 tiles) + gate-exchange xbuf + h-bounce hbuf
#define DYNLDS (2 * TS1 * 2 + 4 * 16 * 16 * 4 + 4 * 16 * 8 * 2)  // 136192 B

typedef _Float16 f16;
typedef _Float16 f16x4 __attribute__((ext_vector_type(4)));
typedef _Float16 f16x8 __attribute__((ext_vector_type(8)));
typedef float f32x4 __attribute__((ext_vector_type(4)));
typedef int i32x4 __attribute__((ext_vector_type(4)));  // native vec: asm "v" ok

#define MFMA16(af, bf, acc) __builtin_amdgcn_mfma_f32_16x16x32_f16((af), (bf), (acc), 0, 0, 0)
#define FSIG(x) (1.f / (1.f + __expf(-(x))))
#define FTANH(x) (1.f - 2.f / (__expf(2.f * (x)) + 1.f))

// ---- prep: x [B][T][D] fp32 -> x16 [T][B][D] fp16 ----
__global__ __launch_bounds__(256) void prep_x_kernel(const float* __restrict__ x,
                                                     f16* __restrict__ x16) {
  int idx = blockIdx.x * 256 + threadIdx.x;
  int d4  = idx & 127;
  int rem = idx >> 7;
  int b   = rem & 63;
  int t   = rem >> 6;
  float4 v = *(const float4*)(x + ((size_t)b * TT + t) * DD + d4 * 4);
  f16x4 o = {(f16)v.x, (f16)v.y, (f16)v.z, (f16)v.w};
  *(f16x4*)(x16 + ((size_t)t * BB + b) * DD + d4 * 4) = o;
}

// ---- persistent 2-layer LSTM ----
// Weights packed in LDS in MFMA-fragment order (conflict-free b128 at lane*16).
// 8 waves = wt(2 weight tiles {i,f},{g,o}) x bt(4 batch tiles).
// Memory model: h stores are sc1 (write-through to LLC); after per-wave
// vmcnt(0)+__syncthreads a RELAXED agent flag store publishes them; consumers
// poll flags then do one agent-ACQUIRE load per wave (emits L1+L2 inv).
// Flat barrier: every block polls all 256 flag lines with 256 threads.
__global__ __launch_bounds__(512, 2) void lstm_persistent(
    const f16* __restrict__ x16,
    const float* __restrict__ Wih0, const float* __restrict__ Whh0,
    const float* __restrict__ bih0, const float* __restrict__ bhh0,
    const float* __restrict__ Wih1, const float* __restrict__ Whh1,
    const float* __restrict__ bih1, const float* __restrict__ bhh1,
    f16* __restrict__ h0g, f16* __restrict__ h1g, int* __restrict__ bar) {
  extern __shared__ f16 lds[];
  const int bid  = blockIdx.x;
  const bool IS1 = (bid >= L0B);
  const int j0   = (IS1 ? bid - L0B : bid) * COLS;
  const int tid  = threadIdx.x;
  const int wv   = tid >> 6;
  const int lane = tid & 63;
  const int wt   = wv >> 2;     // weight tile: 0={i,f}, 1={g,o}
  const int bt   = wv & 3;      // batch tile (16 rows)
  const int col  = lane & 15;
  const int kgrp = lane >> 4;
  const int jc   = col & 7;

  const int CHK = IS1 ? CHK1 : CHK0;
  const int TS  = IS1 ? TS1 : TS0;
  const int DIN = IS1 ? HH : DD;
  f16* Wpk    = lds;
  float* xbuf = (float*)(lds + 2 * TS1);          // [4][16][16] f32
  f16* hbuf   = (f16*)(xbuf + 4 * 16 * 16);       // [4][16][8]

  // ---- prologue: pack weights into fragment order (fp32 -> fp16) ----
  {
    const float* Wi = IS1 ? Wih1 : Wih0;
    const float* Wh = IS1 ? Whh1 : Whh0;
    const int grow = (wt * 2 + ((lane & 15) >> 3)) * HH + j0 + (lane & 7);
    const float* rowi = Wi + (size_t)grow * DIN;
    const float* rowh = Wh + (size_t)grow * HH;
    for (int ck = bt; ck < CHK; ck += 4) {
      int k = ck * 32 + kgrp * 8;
      const float* src = (k < DIN) ? (rowi + k) : (rowh + (k - DIN));
      float4 u = *(const float4*)src;
      float4 v = *(const float4*)(src + 4);
      f16x8 w = {(f16)u.x, (f16)u.y, (f16)u.z, (f16)u.w,
                 (f16)v.x, (f16)v.y, (f16)v.z, (f16)v.w};
      *(f16x8*)(Wpk + (size_t)wt * TS + (size_t)ck * 512 + lane * 8) = w;
    }
  }
  const float* bi = IS1 ? bih1 : bih0;
  const float* bh = IS1 ? bhh1 : bhh0;
  const int bg = wt * 2 + (col >> 3);
  const float bias = bi[bg * HH + j0 + jc] + bh[bg * HH + j0 + jc];
  __syncthreads();

  const int arow = bt * 16 + col;
  float creg[4] = {0.f, 0.f, 0.f, 0.f};
  int* flags = bar;

  for (int s = 0; s <= TT; ++s) {
    const int wrp = s & 1;
    const f16* h0r = h0g + (size_t)(wrp ^ 1) * HSZ;
    const f16* h1r = h1g + (size_t)(wrp ^ 1) * HSZ;
    f16* hw = (IS1 ? h1g : h0g) + (size_t)wrp * HSZ;
    const bool active = IS1 ? (s >= 1) : (s < TT);

    // ---- arrive: drain sc1 h-stores to LLC, then stamp own flag ----
    asm volatile("s_waitcnt vmcnt(0)" ::: "memory");
    __syncthreads();
    if (tid == 0)
      __hip_atomic_store(flags + bid * 32, s + 1, __ATOMIC_RELAXED,
                         __HIP_MEMORY_SCOPE_AGENT);

    f32x4 acc0 = {0.f, 0.f, 0.f, 0.f};
    f32x4 acc1 = {0.f, 0.f, 0.f, 0.f};
    f16x8 af[16];

    // ---- overlap: layer0 x-projection (static input, hides peers' arrival) --
    if (!IS1 && active) {
      const f16* ax = x16 + ((size_t)s * BB + arow) * DD + kgrp * 8;
      const f16* bq = Wpk + (size_t)wt * TS + lane * 8;
      #pragma unroll
      for (int i = 0; i < 16; ++i) af[i] = *(const f16x8*)(ax + i * 32);
      #pragma unroll
      for (int ck = 0; ck < 16; ++ck) {
        f32x4& ac = (ck & 1) ? acc1 : acc0;
        ac = MFMA16(af[ck], *(const f16x8*)(bq + (size_t)ck * 512), ac);
      }
    }

    // ---- flat barrier completion: poll all flags, then per-wave acquire ----
    if (tid < NB)
      while (__hip_atomic_load(flags + tid * 32, __ATOMIC_RELAXED,
                               __HIP_MEMORY_SCOPE_AGENT) < s + 1) {
      }
    __syncthreads();
    (void)__hip_atomic_load(flags + bid * 32, __ATOMIC_ACQUIRE,
                            __HIP_MEMORY_SCOPE_AGENT);  // L1/L2 inv, per wave

    if (active) {
      const f16* bq = Wpk + (size_t)wt * TS + lane * 8;
      if (!IS1) {
        // h0[s-1] part: 32 chunks, 16-deep rolling register prefetch
        const f16* ah = h0r + (size_t)arow * HH + kgrp * 8;
        #pragma unroll
        for (int i = 0; i < 16; ++i) af[i] = *(const f16x8*)(ah + i * 32);
        #pragma unroll
        for (int ck = 0; ck < 32; ++ck) {
          f16x8 a = af[ck & 15];
          if (ck < 16) af[ck] = *(const f16x8*)(ah + (ck + 16) * 32);
          f32x4& ac = (ck & 1) ? acc1 : acc0;
          ac = MFMA16(a, *(const f16x8*)(bq + (size_t)(16 + ck) * 512), ac);
        }
      } else {
        // interleaved h0[s-1] / h1[s-2] stream: 64 chunks, one 16-deep pipeline
        const f16* h0p = h0r + (size_t)arow * HH + kgrp * 8;
        const f16* h1p = h1r + (size_t)arow * HH + kgrp * 8;
        #pragma unroll
        for (int i = 0; i < 16; ++i) {
          const f16* sp = (i & 1) ? h1p : h0p;
          af[i] = *(const f16x8*)(sp + (i >> 1) * 32);
        }
        #pragma unroll
        for (int ck = 0; ck < 64; ++ck) {
          f16x8 a = af[ck & 15];
          int nx = ck + 16;
          if (nx < 64) {
            const f16* sp = (nx & 1) ? h1p : h0p;
            af[ck & 15] = *(const f16x8*)(sp + (nx >> 1) * 32);
          }
          const int bi2 = (ck & 1) * 32 + (ck >> 1);
          f32x4& ac = (ck & 1) ? acc1 : acc0;
          ac = MFMA16(a, *(const f16x8*)(bq + (size_t)bi2 * 512), ac);
        }
      }

      float pv[4];
      #pragma unroll
      for (int r = 0; r < 4; ++r) pv[r] = acc0[r] + acc1[r] + bias;

      // ---- gate exchange: wt=1 publishes tanh(g) / sig(o) ----
      if (wt == 1) {
        #pragma unroll
        for (int r = 0; r < 4; ++r) {
          float a = (col < 8) ? FTANH(pv[r]) : FSIG(pv[r]);
          xbuf[((size_t)bt * 16 + kgrp * 4 + r) * 16 + col] = a;
        }
      }
      __syncthreads();
      // ---- cell update in wt=0 (holds i,f and the c-state) ----
      if (wt == 0) {
        #pragma unroll
        for (int r = 0; r < 4; ++r) {
          float q = __shfl_xor(pv[r], 8);   // partner col+8 holds f-pre
          if (col < 8) {
            float ig = FSIG(pv[r]);
            float fg = FSIG(q);
            const float* xb = xbuf + ((size_t)bt * 16 + kgrp * 4 + r) * 16;
            float gg = xb[jc];
            float og = xb[8 + jc];
            float cc = fg * creg[r] + ig * gg;
            creg[r] = cc;
            hbuf[((size_t)bt * 16 + kgrp * 4 + r) * 8 + jc] = (f16)(og * FTANH(cc));
          }
        }
        // wave-internal transpose bounce -> contiguous 16B h store (sc1: LLC)
        if (lane < 16) {
          f16x8 hv = *(const f16x8*)(hbuf + ((size_t)bt * 16 + lane) * 8);
          f16* dst = hw + (size_t)(bt * 16 + lane) * HH + j0;
          i32x4 hvi;
          __builtin_memcpy(&hvi, &hv, 16);
          asm volatile("global_store_dwordx4 %0, %1, off sc1"
                       :: "v"(dst), "v"(hvi) : "memory");
        }
      }
    }
  }
}

// ---- FC: logits[b][cls] = b_fc[cls] + sum_k concat(h0,h1)[b][k] * Wfc[cls][k]
__global__ __launch_bounds__(256) void fc_kernel(const f16* __restrict__ h0f,
                                                 const f16* __restrict__ h1f,
                                                 const float* __restrict__ Wfc,
                                                 const float* __restrict__ bfc,
                                                 float* __restrict__ out) {
  __shared__ f16 hl[64][264];
  __shared__ float Wl[4][260];
  const int tid = threadIdx.x;
  const int cl0 = blockIdx.x * 4;
  const int b   = tid >> 2;
  const int cq  = tid & 3;
  float a = 0.f;
  for (int k0 = 0; k0 < 2 * HH; k0 += 256) {
    #pragma unroll
    for (int i = 0; i < 8; i++) {
      int v   = tid + i * 256;
      int row = v >> 5;
      int kk  = (v & 31) * 8;
      int kg  = k0 + kk;
      const f16* src = (kg < HH) ? (h0f + (size_t)row * HH + kg)
                                 : (h1f + (size_t)row * HH + (kg - HH));
      *(f16x8*)(&hl[row][kk]) = *(const f16x8*)src;
    }
    {
      int row = tid >> 6;
      int kk  = (tid & 63) * 4;
      *(float4*)(&Wl[row][kk]) = *(const float4*)(Wfc + (size_t)(cl0 + row) * (2 * HH) + k0 + kk);
    }
    __syncthreads();
    #pragma unroll 8
    for (int k = 0; k < 256; k++) a += (float)hl[b][k] * Wl[cq][k];
    __syncthreads();
  }
  out[(size_t)b * NCLS + cl0 + cq] = a + bfc[cl0 + cq];
}

extern "C" void kernel_launch(void* const* d_in, const int* in_sizes, int n_in,
                              void* d_out, int out_size, void* d_ws, size_t ws_size,
                              hipStream_t stream) {
  const float* x    = (const float*)d_in[0];
  const float* Wih0 = (const float*)d_in[1];
  const float* Whh0 = (const float*)d_in[2];
  const float* bih0 = (const float*)d_in[3];
  const float* bhh0 = (const float*)d_in[4];
  const float* Wih1 = (const float*)d_in[5];
  const float* Whh1 = (const float*)d_in[6];
  const float* bih1 = (const float*)d_in[7];
  const float* bhh1 = (const float*)d_in[8];
  const float* Wfc  = (const float*)d_in[9];
  const float* bfc  = (const float*)d_in[10];
  float* out = (float*)d_out;

  char* p = (char*)d_ws;
  auto alloc = [&](size_t bytes) {
    char* r = p;
    p += (bytes + 255) & ~(size_t)255;
    return r;
  };
  f16* x16 = (f16*)alloc((size_t)BB * TT * DD * 2);
  f16* h0g = (f16*)alloc((size_t)2 * HSZ * 2);
  f16* h1g = (f16*)alloc((size_t)2 * HSZ * 2);
  int* bar = (int*)alloc((size_t)(NB * 32 + 32) * 4);

  if ((size_t)(p - (char*)d_ws) > ws_size) return;  // ws too small: bail cleanly

  (void)hipMemsetAsync(bar, 0, (size_t)(NB * 32 + 32) * 4, stream);
  (void)hipMemsetAsync(h0g + (size_t)HSZ, 0, (size_t)HSZ * 2, stream);  // h0[-1]=0 (parity 1)
  (void)hipMemsetAsync(h1g, 0, (size_t)HSZ * 2, stream);                // h1[-1]=0 (parity 0)

  prep_x_kernel<<<dim3(TT * BB * (DD / 4) / 256), dim3(256), 0, stream>>>(x, x16);

  (void)hipFuncSetAttribute((const void*)lstm_persistent,
                            hipFuncAttributeMaxDynamicSharedMemorySize, DYNLDS);
  lstm_persistent<<<dim3(NB), dim3(512), DYNLDS, stream>>>(
      x16, Wih0, Whh0, bih0, bhh0, Wih1, Whh1, bih1, bhh1, h0g, h1g, bar);

  // h0 final: t=255 at s=255 -> parity 1; h1 final: t=255 at s=256 -> parity 0
  fc_kernel<<<dim3(NCLS / 4), dim3(256), 0, stream>>>(
      h0g + (size_t)HSZ, h1g, Wfc, bfc, out);
}

// Round 8
// 4872.953 us; speedup vs baseline: 1.6409x; 1.6409x over previous
//
#include <hip/hip_runtime.h>

#define BB 64
#define TT 256
#define DD 512
#define HH 1024
#define NCLS 1000

#define NB   256       // persistent blocks (1/CU via LDS)
#define L0B  128       // blocks [0,128): layer0; [128,256): layer1
#define COLS 8         // h-columns per block
#define RING 32        // h ring depth; reuse distance makes stale L2 impossible
#define HSZ  (BB * HH) // elements per h snapshot
#define CHK0 48        // K0/32 chunks (512 x + 1024 h)
#define CHK1 64        // K1/32 chunks (1024 h0 + 1024 h1)
#define TS0  (CHK0 * 512)
#define TS1  (CHK1 * 512)
// LDS: packed W frags (2 tiles) + gate-exchange xbuf + h-bounce hbuf
#define DYNLDS (2 * TS1 * 2 + 4 * 16 * 16 * 4 + 4 * 16 * 8 * 2)  // 136192 B

typedef _Float16 f16;
typedef _Float16 f16x4 __attribute__((ext_vector_type(4)));
typedef _Float16 f16x8 __attribute__((ext_vector_type(8)));
typedef float f32x4 __attribute__((ext_vector_type(4)));
typedef int i32x4 __attribute__((ext_vector_type(4)));  // native vec: asm "v" ok

#define MFMA16(af, bf, acc) __builtin_amdgcn_mfma_f32_16x16x32_f16((af), (bf), (acc), 0, 0, 0)
#define FSIG(x) (1.f / (1.f + __expf(-(x))))
#define FTANH(x) (1.f - 2.f / (__expf(2.f * (x)) + 1.f))

// ---- prep: x [B][T][D] fp32 -> x16 [T][B][D] fp16 ----
__global__ __launch_bounds__(256) void prep_x_kernel(const float* __restrict__ x,
                                                     f16* __restrict__ x16) {
  int idx = blockIdx.x * 256 + threadIdx.x;
  int d4  = idx & 127;
  int rem = idx >> 7;
  int b   = rem & 63;
  int t   = rem >> 6;
  float4 v = *(const float4*)(x + ((size_t)b * TT + t) * DD + d4 * 4);
  f16x4 o = {(f16)v.x, (f16)v.y, (f16)v.z, (f16)v.w};
  *(f16x4*)(x16 + ((size_t)t * BB + b) * DD + d4 * 4) = o;
}

// ---- persistent 2-layer LSTM, dataflow (no global barrier) ----
// L0 block j publishes flag0[j]=t+1 after h0[t] (sc1 stores drained, RELEASE).
// L1 block j publishes flag1[j]=u+1 after h1[u].
// L0 @ t needs: flag0[*] >= t (peers' h0[t-1]), flag1[*] >= t-31 (ring free).
// L1 @ u needs: flag1[*] >= u (peers' h1[u-1]), flag0[*] >= u+1 (h0[u] ready).
// Steady state: L0 runs ahead (48 vs 64 chunks), so neither layer waits on the
// other -> each layer paces at own compute + own-peer jitter; L0/L1 overlap.
// No acquire anywhere: ring-32 reuse distance + ~3MB/step/XCD churn evicts any
// stale L2 line long before an address is re-read (R5-proven).
__global__ __launch_bounds__(512, 2) void lstm_persistent(
    const f16* __restrict__ x16,
    const float* __restrict__ Wih0, const float* __restrict__ Whh0,
    const float* __restrict__ bih0, const float* __restrict__ bhh0,
    const float* __restrict__ Wih1, const float* __restrict__ Whh1,
    const float* __restrict__ bih1, const float* __restrict__ bhh1,
    f16* __restrict__ h0ring, f16* __restrict__ h1ring, int* __restrict__ bar) {
  extern __shared__ f16 lds[];
  const int bid  = blockIdx.x;
  const bool IS1 = (bid >= L0B);
  const int j0   = (IS1 ? bid - L0B : bid) * COLS;
  const int tid  = threadIdx.x;
  const int wv   = tid >> 6;
  const int lane = tid & 63;
  const int wt   = wv >> 2;     // weight tile: 0={i,f}, 1={g,o}
  const int bt   = wv & 3;      // batch tile (16 rows)
  const int col  = lane & 15;
  const int kgrp = lane >> 4;
  const int jc   = col & 7;

  const int CHK = IS1 ? CHK1 : CHK0;
  const int TS  = IS1 ? TS1 : TS0;
  const int DIN = IS1 ? HH : DD;
  f16* Wpk    = lds;
  float* xbuf = (float*)(lds + 2 * TS1);          // [4][16][16] f32
  f16* hbuf   = (f16*)(xbuf + 4 * 16 * 16);       // [4][16][8]

  // ---- prologue: pack weights into MFMA-fragment order (fp32 -> fp16) ----
  {
    const float* Wi = IS1 ? Wih1 : Wih0;
    const float* Wh = IS1 ? Whh1 : Whh0;
    const int grow = (wt * 2 + ((lane & 15) >> 3)) * HH + j0 + (lane & 7);
    const float* rowi = Wi + (size_t)grow * DIN;
    const float* rowh = Wh + (size_t)grow * HH;
    for (int ck = bt; ck < CHK; ck += 4) {
      int k = ck * 32 + kgrp * 8;
      const float* src = (k < DIN) ? (rowi + k) : (rowh + (k - DIN));
      float4 u = *(const float4*)src;
      float4 v = *(const float4*)(src + 4);
      f16x8 w = {(f16)u.x, (f16)u.y, (f16)u.z, (f16)u.w,
                 (f16)v.x, (f16)v.y, (f16)v.z, (f16)v.w};
      *(f16x8*)(Wpk + (size_t)wt * TS + (size_t)ck * 512 + lane * 8) = w;
    }
  }
  const float* bi = IS1 ? bih1 : bih0;
  const float* bh = IS1 ? bhh1 : bhh0;
  const int bg = wt * 2 + (col >> 3);
  const float bias = bi[bg * HH + j0 + jc] + bh[bg * HH + j0 + jc];
  __syncthreads();

  const int arow = bt * 16 + col;
  float creg[4] = {0.f, 0.f, 0.f, 0.f};
  int* flag0 = bar;
  int* flag1 = bar + L0B * 32;
  const f16* bq = Wpk + (size_t)wt * TS + lane * 8;

  // shared epilogue: gate exchange + cell update + sc1 h-store
  auto cellstore = [&](f32x4 acc0, f32x4 acc1, f16* hw) {
    float pv[4];
    #pragma unroll
    for (int r = 0; r < 4; ++r) pv[r] = acc0[r] + acc1[r] + bias;
    if (wt == 1) {
      #pragma unroll
      for (int r = 0; r < 4; ++r) {
        float a = (col < 8) ? FTANH(pv[r]) : FSIG(pv[r]);
        xbuf[((size_t)bt * 16 + kgrp * 4 + r) * 16 + col] = a;
      }
    }
    __syncthreads();
    if (wt == 0) {
      #pragma unroll
      for (int r = 0; r < 4; ++r) {
        float q = __shfl_xor(pv[r], 8);   // partner col+8 holds f-pre
        if (col < 8) {
          float ig = FSIG(pv[r]);
          float fg = FSIG(q);
          const float* xb = xbuf + ((size_t)bt * 16 + kgrp * 4 + r) * 16;
          float gg = xb[jc];
          float og = xb[8 + jc];
          float cc = fg * creg[r] + ig * gg;
          creg[r] = cc;
          hbuf[((size_t)bt * 16 + kgrp * 4 + r) * 8 + jc] = (f16)(og * FTANH(cc));
        }
      }
      if (lane < 16) {
        f16x8 hv = *(const f16x8*)(hbuf + ((size_t)bt * 16 + lane) * 8);
        f16* dst = hw + (size_t)(bt * 16 + lane) * HH + j0;
        i32x4 hvi;
        __builtin_memcpy(&hvi, &hv, 16);
        asm volatile("global_store_dwordx4 %0, %1, off sc1"
                     :: "v"(dst), "v"(hvi) : "memory");
      }
    }
  };

  if (!IS1) {
    // ================= layer 0 =================
    for (int t = 0; t < TT; ++t) {
      f32x4 acc0 = {0.f, 0.f, 0.f, 0.f};
      f32x4 acc1 = {0.f, 0.f, 0.f, 0.f};
      // x-projection first: no cross-block dependency, overlaps peers' publish
      const f16* ax = x16 + ((size_t)t * BB + arow) * DD + kgrp * 8;
      #pragma unroll 8
      for (int ck = 0; ck < 16; ++ck) {
        f32x4& ac = (ck & 1) ? acc1 : acc0;
        ac = MFMA16(*(const f16x8*)(ax + ck * 32),
                    *(const f16x8*)(bq + (size_t)ck * 512), ac);
      }
      // deps: peers' h0[t-1]; ring slot free of L1 readers (lag <= 31)
      if (tid < L0B) {
        while (__hip_atomic_load(flag0 + tid * 32, __ATOMIC_RELAXED,
                                 __HIP_MEMORY_SCOPE_AGENT) < t)
          __builtin_amdgcn_s_sleep(2);
      } else if (tid < 2 * L0B) {
        while (__hip_atomic_load(flag1 + (tid - L0B) * 32, __ATOMIC_RELAXED,
                                 __HIP_MEMORY_SCOPE_AGENT) < t - (RING - 1))
          __builtin_amdgcn_s_sleep(2);
      }
      __syncthreads();
      const f16* ah = h0ring + (size_t)((t - 1) & (RING - 1)) * HSZ +
                      (size_t)arow * HH + kgrp * 8;
      #pragma unroll 8
      for (int ck = 0; ck < 32; ++ck) {
        f32x4& ac = (ck & 1) ? acc1 : acc0;
        ac = MFMA16(*(const f16x8*)(ah + ck * 32),
                    *(const f16x8*)(bq + (size_t)(16 + ck) * 512), ac);
      }
      cellstore(acc0, acc1, h0ring + (size_t)(t & (RING - 1)) * HSZ);
      asm volatile("s_waitcnt vmcnt(0)" ::: "memory");
      __syncthreads();
      if (tid == 0)
        __hip_atomic_store(flag0 + bid * 32, t + 1, __ATOMIC_RELEASE,
                           __HIP_MEMORY_SCOPE_AGENT);
    }
  } else {
    // ================= layer 1 =================
    for (int u = 0; u < TT; ++u) {
      // deps: peers' h1[u-1]; L0's h0[u] (L0 runs ahead -> usually satisfied)
      if (tid < L0B) {
        while (__hip_atomic_load(flag1 + tid * 32, __ATOMIC_RELAXED,
                                 __HIP_MEMORY_SCOPE_AGENT) < u)
          __builtin_amdgcn_s_sleep(2);
      } else if (tid < 2 * L0B) {
        while (__hip_atomic_load(flag0 + (tid - L0B) * 32, __ATOMIC_RELAXED,
                                 __HIP_MEMORY_SCOPE_AGENT) < u + 1)
          __builtin_amdgcn_s_sleep(2);
      }
      __syncthreads();
      f32x4 acc0 = {0.f, 0.f, 0.f, 0.f};
      f32x4 acc1 = {0.f, 0.f, 0.f, 0.f};
      const f16* h0p = h0ring + (size_t)(u & (RING - 1)) * HSZ +
                       (size_t)arow * HH + kgrp * 8;
      const f16* h1p = h1ring + (size_t)((u - 1) & (RING - 1)) * HSZ +
                       (size_t)arow * HH + kgrp * 8;
      #pragma unroll 8
      for (int ck = 0; ck < 32; ++ck) {
        f32x4& ac = (ck & 1) ? acc1 : acc0;
        ac = MFMA16(*(const f16x8*)(h0p + ck * 32),
                    *(const f16x8*)(bq + (size_t)ck * 512), ac);
      }
      #pragma unroll 8
      for (int ck = 0; ck < 32; ++ck) {
        f32x4& ac = (ck & 1) ? acc1 : acc0;
        ac = MFMA16(*(const f16x8*)(h1p + ck * 32),
                    *(const f16x8*)(bq + (size_t)(32 + ck) * 512), ac);
      }
      cellstore(acc0, acc1, h1ring + (size_t)(u & (RING - 1)) * HSZ);
      asm volatile("s_waitcnt vmcnt(0)" ::: "memory");
      __syncthreads();
      if (tid == 0)
        __hip_atomic_store(flag1 + (bid - L0B) * 32, u + 1, __ATOMIC_RELEASE,
                           __HIP_MEMORY_SCOPE_AGENT);
    }
  }
}

// ---- FC: logits[b][cls] = b_fc[cls] + sum_k concat(h0,h1)[b][k] * Wfc[cls][k]
__global__ __launch_bounds__(256) void fc_kernel(const f16* __restrict__ h0f,
                                                 const f16* __restrict__ h1f,
                                                 const float* __restrict__ Wfc,
                                                 const float* __restrict__ bfc,
                                                 float* __restrict__ out) {
  __shared__ f16 hl[64][264];
  __shared__ float Wl[4][260];
  const int tid = threadIdx.x;
  const int cl0 = blockIdx.x * 4;
  const int b   = tid >> 2;
  const int cq  = tid & 3;
  float a = 0.f;
  for (int k0 = 0; k0 < 2 * HH; k0 += 256) {
    #pragma unroll
    for (int i = 0; i < 8; i++) {
      int v   = tid + i * 256;
      int row = v >> 5;
      int kk  = (v & 31) * 8;
      int kg  = k0 + kk;
      const f16* src = (kg < HH) ? (h0f + (size_t)row * HH + kg)
                                 : (h1f + (size_t)row * HH + (kg - HH));
      *(f16x8*)(&hl[row][kk]) = *(const f16x8*)src;
    }
    {
      int row = tid >> 6;
      int kk  = (tid & 63) * 4;
      *(float4*)(&Wl[row][kk]) = *(const float4*)(Wfc + (size_t)(cl0 + row) * (2 * HH) + k0 + kk);
    }
    __syncthreads();
    #pragma unroll 8
    for (int k = 0; k < 256; k++) a += (float)hl[b][k] * Wl[cq][k];
    __syncthreads();
  }
  out[(size_t)b * NCLS + cl0 + cq] = a + bfc[cl0 + cq];
}

extern "C" void kernel_launch(void* const* d_in, const int* in_sizes, int n_in,
                              void* d_out, int out_size, void* d_ws, size_t ws_size,
                              hipStream_t stream) {
  const float* x    = (const float*)d_in[0];
  const float* Wih0 = (const float*)d_in[1];
  const float* Whh0 = (const float*)d_in[2];
  const float* bih0 = (const float*)d_in[3];
  const float* bhh0 = (const float*)d_in[4];
  const float* Wih1 = (const float*)d_in[5];
  const float* Whh1 = (const float*)d_in[6];
  const float* bih1 = (const float*)d_in[7];
  const float* bhh1 = (const float*)d_in[8];
  const float* Wfc  = (const float*)d_in[9];
  const float* bfc  = (const float*)d_in[10];
  float* out = (float*)d_out;

  char* p = (char*)d_ws;
  auto alloc = [&](size_t bytes) {
    char* r = p;
    p += (bytes + 255) & ~(size_t)255;
    return r;
  };
  f16* x16    = (f16*)alloc((size_t)BB * TT * DD * 2);
  f16* h0ring = (f16*)alloc((size_t)RING * HSZ * 2);
  f16* h1ring = (f16*)alloc((size_t)RING * HSZ * 2);
  int* bar    = (int*)alloc((size_t)(NB * 32 + 32) * 4);

  if ((size_t)(p - (char*)d_ws) > ws_size) return;  // ws too small: bail cleanly

  (void)hipMemsetAsync(bar, 0, (size_t)(NB * 32 + 32) * 4, stream);
  // slot 31 = t=-1 zeros for both rings
  (void)hipMemsetAsync(h0ring + (size_t)(RING - 1) * HSZ, 0, (size_t)HSZ * 2, stream);
  (void)hipMemsetAsync(h1ring + (size_t)(RING - 1) * HSZ, 0, (size_t)HSZ * 2, stream);

  prep_x_kernel<<<dim3(TT * BB * (DD / 4) / 256), dim3(256), 0, stream>>>(x, x16);

  (void)hipFuncSetAttribute((const void*)lstm_persistent,
                            hipFuncAttributeMaxDynamicSharedMemorySize, DYNLDS);
  lstm_persistent<<<dim3(NB), dim3(512), DYNLDS, stream>>>(
      x16, Wih0, Whh0, bih0, bhh0, Wih1, Whh1, bih1, bhh1, h0ring, h1ring, bar);

  // h0[255] -> slot 255&31 = 31; h1[255] -> slot 31
  fc_kernel<<<dim3(NCLS / 4), dim3(256), 0, stream>>>(
      h0ring + (size_t)(RING - 1) * HSZ, h1ring + (size_t)(RING - 1) * HSZ,
      Wfc, bfc, out);
}

// Round 9
// 4163.063 us; speedup vs baseline: 1.9207x; 1.1705x over previous
//
#include <hip/hip_runtime.h>

#define BB 64
#define TT 256
#define DD 512
#define HH 1024
#define NCLS 1000

#define NB   256       // persistent blocks (1/CU via LDS)
#define L0B  128       // blocks [0,128): layer0; [128,256): layer1
#define COLS 8         // h-columns per block
#define RING 32        // h ring depth; reuse distance makes stale L2 impossible
#define HSZ  (BB * HH) // elements per h snapshot
#define CHK0 48        // K0/32 chunks (512 x + 1024 h)
#define CHK1 64        // K1/32 chunks (1024 h0 + 1024 h1)
#define TS0  (CHK0 * 512)
#define TS1  (CHK1 * 512)
// LDS: packed W frags (2 tiles) + gate-exchange xbuf + h-bounce hbuf
#define DYNLDS (2 * TS1 * 2 + 4 * 16 * 16 * 4 + 4 * 16 * 8 * 2)  // 136192 B
// bar layout (ints): flags0[128 lines], flags1[128 lines], epoch0, epoch1
#define BARWORDS ((2 * L0B + 2) * 32)

typedef _Float16 f16;
typedef _Float16 f16x4 __attribute__((ext_vector_type(4)));
typedef _Float16 f16x8 __attribute__((ext_vector_type(8)));
typedef float f32x4 __attribute__((ext_vector_type(4)));
typedef int i32x4 __attribute__((ext_vector_type(4)));  // native vec: asm "v" ok

#define MFMA16(af, bf, acc) __builtin_amdgcn_mfma_f32_16x16x32_f16((af), (bf), (acc), 0, 0, 0)
#define FSIG(x) (1.f / (1.f + __expf(-(x))))
#define FTANH(x) (1.f - 2.f / (__expf(2.f * (x)) + 1.f))
#define ALOAD __HIP_MEMORY_SCOPE_AGENT

// ---- prep: x [B][T][D] fp32 -> x16 [T][B][D] fp16 ----
__global__ __launch_bounds__(256) void prep_x_kernel(const float* __restrict__ x,
                                                     f16* __restrict__ x16) {
  int idx = blockIdx.x * 256 + threadIdx.x;
  int d4  = idx & 127;
  int rem = idx >> 7;
  int b   = rem & 63;
  int t   = rem >> 6;
  float4 v = *(const float4*)(x + ((size_t)b * TT + t) * DD + d4 * 4);
  f16x4 o = {(f16)v.x, (f16)v.y, (f16)v.z, (f16)v.w};
  *(f16x4*)(x16 + ((size_t)t * BB + b) * DD + d4 * 4) = o;
}

// ---- persistent 2-layer LSTM, dataflow with aggregator-epoch sync ----
// Producer flags (padded lines, relaxed store after vmcnt0 drain of sc1 h
// stores). Per-layer aggregator block polls its layer's 128 flags and
// publishes a single epoch line; all other blocks poll ONLY epoch lines
// (1 thread + s_sleep) -> poll traffic ~0. No acquire: ring-32 reuse + L2
// churn guarantees no stale lines (R5/R7/R8-proven).
//   epoch0 = t  means all L0 finished step t-1 (h0[t-1] readable)
//   epoch1 = u  means all L1 finished step u-1 (h1[u-1] readable, h0 ring
//               slots up to (u-1+32) safe to overwrite)
__global__ __launch_bounds__(512, 2) void lstm_persistent(
    const f16* __restrict__ x16,
    const float* __restrict__ Wih0, const float* __restrict__ Whh0,
    const float* __restrict__ bih0, const float* __restrict__ bhh0,
    const float* __restrict__ Wih1, const float* __restrict__ Whh1,
    const float* __restrict__ bih1, const float* __restrict__ bhh1,
    f16* __restrict__ h0ring, f16* __restrict__ h1ring, int* __restrict__ bar) {
  extern __shared__ f16 lds[];
  const int bid  = blockIdx.x;
  const bool IS1 = (bid >= L0B);
  const int j0   = (IS1 ? bid - L0B : bid) * COLS;
  const int tid  = threadIdx.x;
  const int wv   = tid >> 6;
  const int lane = tid & 63;
  const int wt   = wv >> 2;     // weight tile: 0={i,f}, 1={g,o}
  const int bt   = wv & 3;      // batch tile (16 rows)
  const int col  = lane & 15;
  const int kgrp = lane >> 4;
  const int jc   = col & 7;

  const int CHK = IS1 ? CHK1 : CHK0;
  const int TS  = IS1 ? TS1 : TS0;
  const int DIN = IS1 ? HH : DD;
  f16* Wpk    = lds;
  float* xbuf = (float*)(lds + 2 * TS1);          // [4][16][16] f32
  f16* hbuf   = (f16*)(xbuf + 4 * 16 * 16);       // [4][16][8]

  // ---- prologue: pack weights into MFMA-fragment order (fp32 -> fp16) ----
  {
    const float* Wi = IS1 ? Wih1 : Wih0;
    const float* Wh = IS1 ? Whh1 : Whh0;
    const int grow = (wt * 2 + ((lane & 15) >> 3)) * HH + j0 + (lane & 7);
    const float* rowi = Wi + (size_t)grow * DIN;
    const float* rowh = Wh + (size_t)grow * HH;
    for (int ck = bt; ck < CHK; ck += 4) {
      int k = ck * 32 + kgrp * 8;
      const float* src = (k < DIN) ? (rowi + k) : (rowh + (k - DIN));
      float4 u = *(const float4*)src;
      float4 v = *(const float4*)(src + 4);
      f16x8 w = {(f16)u.x, (f16)u.y, (f16)u.z, (f16)u.w,
                 (f16)v.x, (f16)v.y, (f16)v.z, (f16)v.w};
      *(f16x8*)(Wpk + (size_t)wt * TS + (size_t)ck * 512 + lane * 8) = w;
    }
  }
  const float* bi = IS1 ? bih1 : bih0;
  const float* bh = IS1 ? bhh1 : bhh0;
  const int bg = wt * 2 + (col >> 3);
  const float bias = bi[bg * HH + j0 + jc] + bh[bg * HH + j0 + jc];
  __syncthreads();

  const int arow = bt * 16 + col;
  float creg[4] = {0.f, 0.f, 0.f, 0.f};
  int* flag0  = bar;
  int* flag1  = bar + L0B * 32;
  int* epoch0 = bar + 2 * L0B * 32;
  int* epoch1 = epoch0 + 32;
  const f16* bq = Wpk + (size_t)wt * TS + lane * 8;

  // shared epilogue: gate exchange + cell update + sc1 h-store
  auto cellstore = [&](f32x4 acc0, f32x4 acc1, f16* hw) {
    float pv[4];
    #pragma unroll
    for (int r = 0; r < 4; ++r) pv[r] = acc0[r] + acc1[r] + bias;
    if (wt == 1) {
      #pragma unroll
      for (int r = 0; r < 4; ++r) {
        float a = (col < 8) ? FTANH(pv[r]) : FSIG(pv[r]);
        xbuf[((size_t)bt * 16 + kgrp * 4 + r) * 16 + col] = a;
      }
    }
    __syncthreads();
    if (wt == 0) {
      #pragma unroll
      for (int r = 0; r < 4; ++r) {
        float q = __shfl_xor(pv[r], 8);   // partner col+8 holds f-pre
        if (col < 8) {
          float ig = FSIG(pv[r]);
          float fg = FSIG(q);
          const float* xb = xbuf + ((size_t)bt * 16 + kgrp * 4 + r) * 16;
          float gg = xb[jc];
          float og = xb[8 + jc];
          float cc = fg * creg[r] + ig * gg;
          creg[r] = cc;
          hbuf[((size_t)bt * 16 + kgrp * 4 + r) * 8 + jc] = (f16)(og * FTANH(cc));
        }
      }
      if (lane < 16) {
        f16x8 hv = *(const f16x8*)(hbuf + ((size_t)bt * 16 + lane) * 8);
        f16* dst = hw + (size_t)(bt * 16 + lane) * HH + j0;
        i32x4 hvi;
        __builtin_memcpy(&hvi, &hv, 16);
        asm volatile("global_store_dwordx4 %0, %1, off sc1"
                     :: "v"(dst), "v"(hvi) : "memory");
      }
    }
  };

  // 32-chunk matmul: load-all -> sched_barrier -> MFMA (forced MLP=32)
  auto mm32 = [&](const f16* ap, int bbase, f32x4& acc0, f32x4& acc1) {
    f16x8 af[32];
    #pragma unroll
    for (int ck = 0; ck < 32; ++ck) af[ck] = *(const f16x8*)(ap + ck * 32);
    __builtin_amdgcn_sched_barrier(0);
    #pragma unroll
    for (int ck = 0; ck < 32; ++ck) {
      f32x4& ac = (ck & 1) ? acc1 : acc0;
      ac = MFMA16(af[ck], *(const f16x8*)(bq + (size_t)(bbase + ck) * 512), ac);
    }
  };

  if (!IS1) {
    // ================= layer 0 =================
    const bool AGG = (bid == 0);
    for (int t = 0; t < TT; ++t) {
      f32x4 acc0 = {0.f, 0.f, 0.f, 0.f};
      f32x4 acc1 = {0.f, 0.f, 0.f, 0.f};
      // x-projection: no cross-block dep; hides peers' publish + detection
      {
        const f16* ax = x16 + ((size_t)t * BB + arow) * DD + kgrp * 8;
        f16x8 af[16];
        #pragma unroll
        for (int ck = 0; ck < 16; ++ck) af[ck] = *(const f16x8*)(ax + ck * 32);
        __builtin_amdgcn_sched_barrier(0);
        #pragma unroll
        for (int ck = 0; ck < 16; ++ck) {
          f32x4& ac = (ck & 1) ? acc1 : acc0;
          ac = MFMA16(af[ck], *(const f16x8*)(bq + (size_t)ck * 512), ac);
        }
      }
      // wait: peers' h0[t-1] ready; h0 ring slot free of L1 readers
      if (AGG) {
        if (tid < L0B)
          while (__hip_atomic_load(flag0 + tid * 32, __ATOMIC_RELAXED, ALOAD) < t)
            __builtin_amdgcn_s_sleep(2);
      } else if (tid == 0) {
        while (__hip_atomic_load(epoch0, __ATOMIC_RELAXED, ALOAD) < t)
          __builtin_amdgcn_s_sleep(4);
      }
      if (tid == 256) {
        while (__hip_atomic_load(epoch1, __ATOMIC_RELAXED, ALOAD) < t - (RING - 1))
          __builtin_amdgcn_s_sleep(4);
      }
      __syncthreads();
      if (AGG && tid == 0)
        __hip_atomic_store(epoch0, t, __ATOMIC_RELAXED, ALOAD);

      const f16* ah = h0ring + (size_t)((t - 1) & (RING - 1)) * HSZ +
                      (size_t)arow * HH + kgrp * 8;
      mm32(ah, 16, acc0, acc1);
      cellstore(acc0, acc1, h0ring + (size_t)(t & (RING - 1)) * HSZ);
      asm volatile("s_waitcnt vmcnt(0)" ::: "memory");
      __syncthreads();
      if (tid == 0)
        __hip_atomic_store(flag0 + bid * 32, t + 1, __ATOMIC_RELAXED, ALOAD);
    }
    // final epoch0 pass: publish 256 for L1's last step
    if (AGG) {
      if (tid < L0B)
        while (__hip_atomic_load(flag0 + tid * 32, __ATOMIC_RELAXED, ALOAD) < TT)
          __builtin_amdgcn_s_sleep(2);
      __syncthreads();
      if (tid == 0)
        __hip_atomic_store(epoch0, TT, __ATOMIC_RELAXED, ALOAD);
    }
  } else {
    // ================= layer 1 =================
    const bool AGG = (bid == L0B);
    for (int u = 0; u < TT; ++u) {
      // h0[u] ready? (L0 runs up to 31 ahead -> nearly always satisfied)
      if (tid == 0)
        while (__hip_atomic_load(epoch0, __ATOMIC_RELAXED, ALOAD) < u + 1)
          __builtin_amdgcn_s_sleep(4);
      __syncthreads();
      f32x4 acc0 = {0.f, 0.f, 0.f, 0.f};
      f32x4 acc1 = {0.f, 0.f, 0.f, 0.f};
      const f16* h0p = h0ring + (size_t)(u & (RING - 1)) * HSZ +
                       (size_t)arow * HH + kgrp * 8;
      mm32(h0p, 0, acc0, acc1);   // overlaps peers' h1[u-1] publish
      // wait: peers' h1[u-1]
      if (AGG) {
        if (tid < L0B)
          while (__hip_atomic_load(flag1 + tid * 32, __ATOMIC_RELAXED, ALOAD) < u)
            __builtin_amdgcn_s_sleep(2);
      } else if (tid == 0) {
        while (__hip_atomic_load(epoch1, __ATOMIC_RELAXED, ALOAD) < u)
          __builtin_amdgcn_s_sleep(4);
      }
      __syncthreads();
      if (AGG && tid == 0)
        __hip_atomic_store(epoch1, u, __ATOMIC_RELAXED, ALOAD);

      const f16* h1p = h1ring + (size_t)((u - 1) & (RING - 1)) * HSZ +
                       (size_t)arow * HH + kgrp * 8;
      mm32(h1p, 32, acc0, acc1);
      cellstore(acc0, acc1, h1ring + (size_t)(u & (RING - 1)) * HSZ);
      asm volatile("s_waitcnt vmcnt(0)" ::: "memory");
      __syncthreads();
      if (tid == 0)
        __hip_atomic_store(flag1 + (bid - L0B) * 32, u + 1, __ATOMIC_RELAXED, ALOAD);
    }
  }
}

// ---- FC: logits[b][cls] = b_fc[cls] + sum_k concat(h0,h1)[b][k] * Wfc[cls][k]
__global__ __launch_bounds__(256) void fc_kernel(const f16* __restrict__ h0f,
                                                 const f16* __restrict__ h1f,
                                                 const float* __restrict__ Wfc,
                                                 const float* __restrict__ bfc,
                                                 float* __restrict__ out) {
  __shared__ f16 hl[64][264];
  __shared__ float Wl[4][260];
  const int tid = threadIdx.x;
  const int cl0 = blockIdx.x * 4;
  const int b   = tid >> 2;
  const int cq  = tid & 3;
  float a = 0.f;
  for (int k0 = 0; k0 < 2 * HH; k0 += 256) {
    #pragma unroll
    for (int i = 0; i < 8; i++) {
      int v   = tid + i * 256;
      int row = v >> 5;
      int kk  = (v & 31) * 8;
      int kg  = k0 + kk;
      const f16* src = (kg < HH) ? (h0f + (size_t)row * HH + kg)
                                 : (h1f + (size_t)row * HH + (kg - HH));
      *(f16x8*)(&hl[row][kk]) = *(const f16x8*)src;
    }
    {
      int row = tid >> 6;
      int kk  = (tid & 63) * 4;
      *(float4*)(&Wl[row][kk]) = *(const float4*)(Wfc + (size_t)(cl0 + row) * (2 * HH) + k0 + kk);
    }
    __syncthreads();
    #pragma unroll 8
    for (int k = 0; k < 256; k++) a += (float)hl[b][k] * Wl[cq][k];
    __syncthreads();
  }
  out[(size_t)b * NCLS + cl0 + cq] = a + bfc[cl0 + cq];
}

extern "C" void kernel_launch(void* const* d_in, const int* in_sizes, int n_in,
                              void* d_out, int out_size, void* d_ws, size_t ws_size,
                              hipStream_t stream) {
  const float* x    = (const float*)d_in[0];
  const float* Wih0 = (const float*)d_in[1];
  const float* Whh0 = (const float*)d_in[2];
  const float* bih0 = (const float*)d_in[3];
  const float* bhh0 = (const float*)d_in[4];
  const float* Wih1 = (const float*)d_in[5];
  const float* Whh1 = (const float*)d_in[6];
  const float* bih1 = (const float*)d_in[7];
  const float* bhh1 = (const float*)d_in[8];
  const float* Wfc  = (const float*)d_in[9];
  const float* bfc  = (const float*)d_in[10];
  float* out = (float*)d_out;

  char* p = (char*)d_ws;
  auto alloc = [&](size_t bytes) {
    char* r = p;
    p += (bytes + 255) & ~(size_t)255;
    return r;
  };
  f16* x16    = (f16*)alloc((size_t)BB * TT * DD * 2);
  f16* h0ring = (f16*)alloc((size_t)RING * HSZ * 2);
  f16* h1ring = (f16*)alloc((size_t)RING * HSZ * 2);
  int* bar    = (int*)alloc((size_t)BARWORDS * 4);

  if ((size_t)(p - (char*)d_ws) > ws_size) return;  // ws too small: bail cleanly

  (void)hipMemsetAsync(bar, 0, (size_t)BARWORDS * 4, stream);
  // slot 31 = t=-1 zeros for both rings
  (void)hipMemsetAsync(h0ring + (size_t)(RING - 1) * HSZ, 0, (size_t)HSZ * 2, stream);
  (void)hipMemsetAsync(h1ring + (size_t)(RING - 1) * HSZ, 0, (size_t)HSZ * 2, stream);

  prep_x_kernel<<<dim3(TT * BB * (DD / 4) / 256), dim3(256), 0, stream>>>(x, x16);

  (void)hipFuncSetAttribute((const void*)lstm_persistent,
                            hipFuncAttributeMaxDynamicSharedMemorySize, DYNLDS);
  lstm_persistent<<<dim3(NB), dim3(512), DYNLDS, stream>>>(
      x16, Wih0, Whh0, bih0, bhh0, Wih1, Whh1, bih1, bhh1, h0ring, h1ring, bar);

  // h0[255] -> slot 255&31 = 31; h1[255] -> slot 31
  fc_kernel<<<dim3(NCLS / 4), dim3(256), 0, stream>>>(
      h0ring + (size_t)(RING - 1) * HSZ, h1ring + (size_t)(RING - 1) * HSZ,
      Wfc, bfc, out);
}

// Round 10
// 4157.047 us; speedup vs baseline: 1.9235x; 1.0014x over previous
//
#include <hip/hip_runtime.h>

#define BB 64
#define TT 256
#define DD 512
#define HH 1024
#define NCLS 1000

#define NB   256       // persistent blocks (1/CU via LDS)
#define L0B  128       // blocks [0,128): layer0; [128,256): layer1
#define COLS 8         // h-columns per block
#define RING 32        // h ring depth; reuse distance makes stale L2 impossible
#define HSZ  (BB * HH) // elements per h snapshot
#define CHK0 48        // K0/32 chunks (512 x + 1024 h)
#define CHK1 64        // K1/32 chunks (1024 h0 + 1024 h1)
#define TS0  (CHK0 * 512)
#define TS1  (CHK1 * 512)
// LDS: packed W frags (2 tiles) + gate-exchange xbuf + h-bounce hbuf
#define DYNLDS (2 * TS1 * 2 + 4 * 16 * 16 * 4 + 4 * 16 * 8 * 2)  // 136192 B
// bar layout (ints): flags0[128 lines], flags1[128 lines], epoch0, epoch1
#define BARWORDS ((2 * L0B + 2) * 32)

typedef _Float16 f16;
typedef _Float16 f16x4 __attribute__((ext_vector_type(4)));
typedef _Float16 f16x8 __attribute__((ext_vector_type(8)));
typedef float f32x4 __attribute__((ext_vector_type(4)));
typedef int i32x4 __attribute__((ext_vector_type(4)));

#define MFMA16(af, bf, acc) __builtin_amdgcn_mfma_f32_16x16x32_f16((af), (bf), (acc), 0, 0, 0)
#define FSIG(x) (1.f / (1.f + __expf(-(x))))
#define FTANH(x) (1.f - 2.f / (__expf(2.f * (x)) + 1.f))
#define ALOAD __HIP_MEMORY_SCOPE_AGENT

// ---- asm-forced deep load pipeline -------------------------------------
// glN: issue N global_load_dwordx4 from one base with compile-time offsets.
// asm volatile => the compiler cannot elide, split, or sink them: N loads
// are genuinely outstanding (vmcnt = N).
template <int N, int I = 0>
__device__ __forceinline__ void glN(i32x4* A, const f16* base) {
  if constexpr (I < N) {
    asm volatile("global_load_dwordx4 %0, %1, off offset:%2"
                 : "=v"(A[I]) : "v"(base), "n"(I * 64));
    glN<N, I + 1>(A, base);
  }
}
// mfN: consume TOTAL chunks in groups of 8 behind progressive counted
// s_waitcnt vmcnt(TOTAL-(G+1)*8+EXTRA); EXTRA = loads issued after this
// stream (FIFO vmcnt semantics). sched_barrier(0) pins the register-only
// MFMAs behind the wait (guide rule #18).
template <int TOTAL, int EXTRA, int BBASE, int G = 0>
__device__ __forceinline__ void mfN(i32x4* A, const f16* bq,
                                    f32x4& acc0, f32x4& acc1) {
  if constexpr (G * 8 < TOTAL) {
    asm volatile("s_waitcnt vmcnt(%0)" :: "n"(TOTAL - (G + 1) * 8 + EXTRA)
                 : "memory");
    __builtin_amdgcn_sched_barrier(0);
    #pragma unroll
    for (int k = 0; k < 8; ++k) {
      constexpr int ckb = G * 8;
      int ck = ckb + k;
      f16x8 a;
      __builtin_memcpy(&a, &A[ck], 16);
      f32x4& ac = (ck & 1) ? acc1 : acc0;
      ac = MFMA16(a, *(const f16x8*)(bq + (size_t)(BBASE + ck) * 512), ac);
    }
    mfN<TOTAL, EXTRA, BBASE, G + 1>(A, bq, acc0, acc1);
  }
}

// ---- prep: x [B][T][D] fp32 -> x16 [T][B][D] fp16 ----
__global__ __launch_bounds__(256) void prep_x_kernel(const float* __restrict__ x,
                                                     f16* __restrict__ x16) {
  int idx = blockIdx.x * 256 + threadIdx.x;
  int d4  = idx & 127;
  int rem = idx >> 7;
  int b   = rem & 63;
  int t   = rem >> 6;
  float4 v = *(const float4*)(x + ((size_t)b * TT + t) * DD + d4 * 4);
  f16x4 o = {(f16)v.x, (f16)v.y, (f16)v.z, (f16)v.w};
  *(f16x4*)(x16 + ((size_t)t * BB + b) * DD + d4 * 4) = o;
}

// ---- persistent 2-layer LSTM, dataflow + aggregator epochs + asm MLP ----
__global__ __launch_bounds__(512, 2) void lstm_persistent(
    const f16* __restrict__ x16,
    const float* __restrict__ Wih0, const float* __restrict__ Whh0,
    const float* __restrict__ bih0, const float* __restrict__ bhh0,
    const float* __restrict__ Wih1, const float* __restrict__ Whh1,
    const float* __restrict__ bih1, const float* __restrict__ bhh1,
    f16* __restrict__ h0ring, f16* __restrict__ h1ring, int* __restrict__ bar) {
  extern __shared__ f16 lds[];
  const int bid  = blockIdx.x;
  const bool IS1 = (bid >= L0B);
  const int j0   = (IS1 ? bid - L0B : bid) * COLS;
  const int tid  = threadIdx.x;
  const int wv   = tid >> 6;
  const int lane = tid & 63;
  const int wt   = wv >> 2;     // weight tile: 0={i,f}, 1={g,o}
  const int bt   = wv & 3;      // batch tile (16 rows)
  const int col  = lane & 15;
  const int kgrp = lane >> 4;
  const int jc   = col & 7;

  const int CHK = IS1 ? CHK1 : CHK0;
  const int TS  = IS1 ? TS1 : TS0;
  const int DIN = IS1 ? HH : DD;
  f16* Wpk    = lds;
  float* xbuf = (float*)(lds + 2 * TS1);          // [4][16][16] f32
  f16* hbuf   = (f16*)(xbuf + 4 * 16 * 16);       // [4][16][8]

  // ---- prologue: pack weights into MFMA-fragment order (fp32 -> fp16) ----
  {
    const float* Wi = IS1 ? Wih1 : Wih0;
    const float* Wh = IS1 ? Whh1 : Whh0;
    const int grow = (wt * 2 + ((lane & 15) >> 3)) * HH + j0 + (lane & 7);
    const float* rowi = Wi + (size_t)grow * DIN;
    const float* rowh = Wh + (size_t)grow * HH;
    for (int ck = bt; ck < CHK; ck += 4) {
      int k = ck * 32 + kgrp * 8;
      const float* src = (k < DIN) ? (rowi + k) : (rowh + (k - DIN));
      float4 u = *(const float4*)src;
      float4 v = *(const float4*)(src + 4);
      f16x8 w = {(f16)u.x, (f16)u.y, (f16)u.z, (f16)u.w,
                 (f16)v.x, (f16)v.y, (f16)v.z, (f16)v.w};
      *(f16x8*)(Wpk + (size_t)wt * TS + (size_t)ck * 512 + lane * 8) = w;
    }
  }
  const float* bi = IS1 ? bih1 : bih0;
  const float* bh = IS1 ? bhh1 : bhh0;
  const int bg = wt * 2 + (col >> 3);
  const float bias = bi[bg * HH + j0 + jc] + bh[bg * HH + j0 + jc];
  __syncthreads();

  const int arow = bt * 16 + col;
  float creg[4] = {0.f, 0.f, 0.f, 0.f};
  int* flag0  = bar;
  int* flag1  = bar + L0B * 32;
  int* epoch0 = bar + 2 * L0B * 32;
  int* epoch1 = epoch0 + 32;
  const f16* bq = Wpk + (size_t)wt * TS + lane * 8;

  // shared epilogue: gate exchange + cell update + sc1 h-store
  auto cellstore = [&](f32x4 acc0, f32x4 acc1, f16* hw) {
    float pv[4];
    #pragma unroll
    for (int r = 0; r < 4; ++r) pv[r] = acc0[r] + acc1[r] + bias;
    if (wt == 1) {
      #pragma unroll
      for (int r = 0; r < 4; ++r) {
        float a = (col < 8) ? FTANH(pv[r]) : FSIG(pv[r]);
        xbuf[((size_t)bt * 16 + kgrp * 4 + r) * 16 + col] = a;
      }
    }
    __syncthreads();
    if (wt == 0) {
      #pragma unroll
      for (int r = 0; r < 4; ++r) {
        float q = __shfl_xor(pv[r], 8);   // partner col+8 holds f-pre
        if (col < 8) {
          float ig = FSIG(pv[r]);
          float fg = FSIG(q);
          const float* xb = xbuf + ((size_t)bt * 16 + kgrp * 4 + r) * 16;
          float gg = xb[jc];
          float og = xb[8 + jc];
          float cc = fg * creg[r] + ig * gg;
          creg[r] = cc;
          hbuf[((size_t)bt * 16 + kgrp * 4 + r) * 8 + jc] = (f16)(og * FTANH(cc));
        }
      }
      if (lane < 16) {
        f16x8 hv = *(const f16x8*)(hbuf + ((size_t)bt * 16 + lane) * 8);
        f16* dst = hw + (size_t)(bt * 16 + lane) * HH + j0;
        i32x4 hvi;
        __builtin_memcpy(&hvi, &hv, 16);
        asm volatile("global_store_dwordx4 %0, %1, off sc1"
                     :: "v"(dst), "v"(hvi) : "memory");
      }
    }
  };

  if (!IS1) {
    // ================= layer 0 =================
    const bool AGG = (bid == 0);
    i32x4 afx[16], afh[32];
    for (int t = 0; t < TT; ++t) {
      // 1. x-loads in flight (no cross-block dep)
      const f16* ax = x16 + ((size_t)t * BB + arow) * DD + kgrp * 8;
      glN<16>(afx, ax);
      // 2. wait peers' h0[t-1]; ring slot free of L1 readers (x flight hides)
      if (AGG) {
        if (tid < L0B)
          while (__hip_atomic_load(flag0 + tid * 32, __ATOMIC_RELAXED, ALOAD) < t)
            __builtin_amdgcn_s_sleep(1);
      } else if (tid == 0) {
        while (__hip_atomic_load(epoch0, __ATOMIC_RELAXED, ALOAD) < t)
          __builtin_amdgcn_s_sleep(2);
      }
      if (tid == 256) {
        while (__hip_atomic_load(epoch1, __ATOMIC_RELAXED, ALOAD) < t - (RING - 1))
          __builtin_amdgcn_s_sleep(2);
      }
      __syncthreads();
      if (AGG && tid == 0)
        __hip_atomic_store(epoch0, t, __ATOMIC_RELAXED, ALOAD);
      // 3. h-loads in flight behind x
      const f16* ah = h0ring + (size_t)((t - 1) & (RING - 1)) * HSZ +
                      (size_t)arow * HH + kgrp * 8;
      glN<32>(afh, ah);
      // 4. consume x (vmcnt 40,32), then h (24..0)
      f32x4 acc0 = {0.f, 0.f, 0.f, 0.f};
      f32x4 acc1 = {0.f, 0.f, 0.f, 0.f};
      mfN<16, 32, 0>(afx, bq, acc0, acc1);
      mfN<32, 0, 16>(afh, bq, acc0, acc1);
      cellstore(acc0, acc1, h0ring + (size_t)(t & (RING - 1)) * HSZ);
      asm volatile("s_waitcnt vmcnt(0)" ::: "memory");
      __syncthreads();
      if (tid == 0)
        __hip_atomic_store(flag0 + bid * 32, t + 1, __ATOMIC_RELAXED, ALOAD);
    }
    // final epoch0 pass for L1's last step
    if (AGG) {
      if (tid < L0B)
        while (__hip_atomic_load(flag0 + tid * 32, __ATOMIC_RELAXED, ALOAD) < TT)
          __builtin_amdgcn_s_sleep(1);
      __syncthreads();
      if (tid == 0)
        __hip_atomic_store(epoch0, TT, __ATOMIC_RELAXED, ALOAD);
    }
  } else {
    // ================= layer 1 =================
    const bool AGG = (bid == L0B);
    i32x4 af[32];
    for (int u = 0; u < TT; ++u) {
      // 1. h0[u] ready? (L0 runs ahead -> nearly always satisfied)
      if (tid == 0)
        while (__hip_atomic_load(epoch0, __ATOMIC_RELAXED, ALOAD) < u + 1)
          __builtin_amdgcn_s_sleep(2);
      __syncthreads();
      // 2. h0 loads in flight
      const f16* h0p = h0ring + (size_t)(u & (RING - 1)) * HSZ +
                       (size_t)arow * HH + kgrp * 8;
      glN<32>(af, h0p);
      // 3. wait peers' h1[u-1] WHILE h0 loads fly
      if (AGG) {
        if (tid < L0B)
          while (__hip_atomic_load(flag1 + tid * 32, __ATOMIC_RELAXED, ALOAD) < u)
            __builtin_amdgcn_s_sleep(1);
      } else if (tid == 0) {
        while (__hip_atomic_load(epoch1, __ATOMIC_RELAXED, ALOAD) < u)
          __builtin_amdgcn_s_sleep(2);
      }
      __syncthreads();
      if (AGG && tid == 0)
        __hip_atomic_store(epoch1, u, __ATOMIC_RELAXED, ALOAD);
      // 4. consume h0 (24..0)
      f32x4 acc0 = {0.f, 0.f, 0.f, 0.f};
      f32x4 acc1 = {0.f, 0.f, 0.f, 0.f};
      mfN<32, 0, 0>(af, bq, acc0, acc1);
      // 5. h1 loads + consume (24..0)
      const f16* h1p = h1ring + (size_t)((u - 1) & (RING - 1)) * HSZ +
                       (size_t)arow * HH + kgrp * 8;
      glN<32>(af, h1p);
      mfN<32, 0, 32>(af, bq, acc0, acc1);
      cellstore(acc0, acc1, h1ring + (size_t)(u & (RING - 1)) * HSZ);
      asm volatile("s_waitcnt vmcnt(0)" ::: "memory");
      __syncthreads();
      if (tid == 0)
        __hip_atomic_store(flag1 + (bid - L0B) * 32, u + 1, __ATOMIC_RELAXED, ALOAD);
    }
  }
}

// ---- FC: logits[b][cls] = b_fc[cls] + sum_k concat(h0,h1)[b][k] * Wfc[cls][k]
__global__ __launch_bounds__(256) void fc_kernel(const f16* __restrict__ h0f,
                                                 const f16* __restrict__ h1f,
                                                 const float* __restrict__ Wfc,
                                                 const float* __restrict__ bfc,
                                                 float* __restrict__ out) {
  __shared__ f16 hl[64][264];
  __shared__ float Wl[4][260];
  const int tid = threadIdx.x;
  const int cl0 = blockIdx.x * 4;
  const int b   = tid >> 2;
  const int cq  = tid & 3;
  float a = 0.f;
  for (int k0 = 0; k0 < 2 * HH; k0 += 256) {
    #pragma unroll
    for (int i = 0; i < 8; i++) {
      int v   = tid + i * 256;
      int row = v >> 5;
      int kk  = (v & 31) * 8;
      int kg  = k0 + kk;
      const f16* src = (kg < HH) ? (h0f + (size_t)row * HH + kg)
                                 : (h1f + (size_t)row * HH + (kg - HH));
      *(f16x8*)(&hl[row][kk]) = *(const f16x8*)src;
    }
    {
      int row = tid >> 6;
      int kk  = (tid & 63) * 4;
      *(float4*)(&Wl[row][kk]) = *(const float4*)(Wfc + (size_t)(cl0 + row) * (2 * HH) + k0 + kk);
    }
    __syncthreads();
    #pragma unroll 8
    for (int k = 0; k < 256; k++) a += (float)hl[b][k] * Wl[cq][k];
    __syncthreads();
  }
  out[(size_t)b * NCLS + cl0 + cq] = a + bfc[cl0 + cq];
}

extern "C" void kernel_launch(void* const* d_in, const int* in_sizes, int n_in,
                              void* d_out, int out_size, void* d_ws, size_t ws_size,
                              hipStream_t stream) {
  const float* x    = (const float*)d_in[0];
  const float* Wih0 = (const float*)d_in[1];
  const float* Whh0 = (const float*)d_in[2];
  const float* bih0 = (const float*)d_in[3];
  const float* bhh0 = (const float*)d_in[4];
  const float* Wih1 = (const float*)d_in[5];
  const float* Whh1 = (const float*)d_in[6];
  const float* bih1 = (const float*)d_in[7];
  const float* bhh1 = (const float*)d_in[8];
  const float* Wfc  = (const float*)d_in[9];
  const float* bfc  = (const float*)d_in[10];
  float* out = (float*)d_out;

  char* p = (char*)d_ws;
  auto alloc = [&](size_t bytes) {
    char* r = p;
    p += (bytes + 255) & ~(size_t)255;
    return r;
  };
  f16* x16    = (f16*)alloc((size_t)BB * TT * DD * 2);
  f16* h0ring = (f16*)alloc((size_t)RING * HSZ * 2);
  f16* h1ring = (f16*)alloc((size_t)RING * HSZ * 2);
  int* bar    = (int*)alloc((size_t)BARWORDS * 4);

  if ((size_t)(p - (char*)d_ws) > ws_size) return;  // ws too small: bail cleanly

  (void)hipMemsetAsync(bar, 0, (size_t)BARWORDS * 4, stream);
  // slot 31 = t=-1 zeros for both rings
  (void)hipMemsetAsync(h0ring + (size_t)(RING - 1) * HSZ, 0, (size_t)HSZ * 2, stream);
  (void)hipMemsetAsync(h1ring + (size_t)(RING - 1) * HSZ, 0, (size_t)HSZ * 2, stream);

  prep_x_kernel<<<dim3(TT * BB * (DD / 4) / 256), dim3(256), 0, stream>>>(x, x16);

  (void)hipFuncSetAttribute((const void*)lstm_persistent,
                            hipFuncAttributeMaxDynamicSharedMemorySize, DYNLDS);
  lstm_persistent<<<dim3(NB), dim3(512), DYNLDS, stream>>>(
      x16, Wih0, Whh0, bih0, bhh0, Wih1, Whh1, bih1, bhh1, h0ring, h1ring, bar);

  // h0[255] -> slot 255&31 = 31; h1[255] -> slot 31
  fc_kernel<<<dim3(NCLS / 4), dim3(256), 0, stream>>>(
      h0ring + (size_t)(RING - 1) * HSZ, h1ring + (size_t)(RING - 1) * HSZ,
      Wfc, bfc, out);
}

// Round 11
// 4150.431 us; speedup vs baseline: 1.9265x; 1.0016x over previous
//
#include <hip/hip_runtime.h>

#define BB 64
#define TT 256
#define DD 512
#define HH 1024
#define NCLS 1000

#define NB   256       // persistent blocks (1/CU via LDS)
#define L0B  128       // blocks [0,128): layer0; [128,256): layer1
#define COLS 8         // h-columns per block
#define RING 32        // h ring depth; reuse distance makes stale L2 impossible
#define HSZ  (BB * HH) // elements per h snapshot
#define CHK0 48        // K0/32 chunks (512 x + 1024 h)
#define CHK1 64        // K1/32 chunks (1024 h0 + 1024 h1)
#define TS0  (CHK0 * 512)
#define TS1  (CHK1 * 512)
#define GRP  32        // epoch replica lines (contention fix: ~8 pollers/line)
#define EPSLP 16       // epoch poll sleep (~0.43us >> LLC line service time)
// LDS: packed W frags (2 tiles) + gate-exchange xbuf + h-bounce hbuf
#define DYNLDS (2 * TS1 * 2 + 4 * 16 * 16 * 4 + 4 * 16 * 8 * 2)  // 136192 B
// bar: flags0[128 lines], flags1[128 lines], ep0rep[32 lines], ep1rep[32 lines]
#define BARWORDS ((2 * L0B + 2 * GRP) * 32)

typedef _Float16 f16;
typedef _Float16 f16x4 __attribute__((ext_vector_type(4)));
typedef _Float16 f16x8 __attribute__((ext_vector_type(8)));
typedef float f32x4 __attribute__((ext_vector_type(4)));
typedef int i32x4 __attribute__((ext_vector_type(4)));

#define MFMA16(af, bf, acc) __builtin_amdgcn_mfma_f32_16x16x32_f16((af), (bf), (acc), 0, 0, 0)
#define FSIG(x) (1.f / (1.f + __expf(-(x))))
#define FTANH(x) (1.f - 2.f / (__expf(2.f * (x)) + 1.f))
#define ALOAD __HIP_MEMORY_SCOPE_AGENT

// ---- asm-forced deep load pipeline (proven: VGPR 100->128, loads in flight) --
template <int N, int I = 0>
__device__ __forceinline__ void glN(i32x4* A, const f16* base) {
  if constexpr (I < N) {
    asm volatile("global_load_dwordx4 %0, %1, off offset:%2"
                 : "=v"(A[I]) : "v"(base), "n"(I * 64));
    glN<N, I + 1>(A, base);
  }
}
// consume TOTAL chunks in groups of 8 behind progressive counted vmcnt
template <int TOTAL, int EXTRA, int BBASE, int G = 0>
__device__ __forceinline__ void mfN(i32x4* A, const f16* bq,
                                    f32x4& acc0, f32x4& acc1) {
  if constexpr (G * 8 < TOTAL) {
    asm volatile("s_waitcnt vmcnt(%0)" :: "n"(TOTAL - (G + 1) * 8 + EXTRA)
                 : "memory");
    __builtin_amdgcn_sched_barrier(0);
    #pragma unroll
    for (int k = 0; k < 8; ++k) {
      constexpr int ckb = G * 8;
      int ck = ckb + k;
      f16x8 a;
      __builtin_memcpy(&a, &A[ck], 16);
      f32x4& ac = (ck & 1) ? acc1 : acc0;
      ac = MFMA16(a, *(const f16x8*)(bq + (size_t)(BBASE + ck) * 512), ac);
    }
    mfN<TOTAL, EXTRA, BBASE, G + 1>(A, bq, acc0, acc1);
  }
}

// ---- prep: x [B][T][D] fp32 -> x16 [T][B][D] fp16 ----
__global__ __launch_bounds__(256) void prep_x_kernel(const float* __restrict__ x,
                                                     f16* __restrict__ x16) {
  int idx = blockIdx.x * 256 + threadIdx.x;
  int d4  = idx & 127;
  int rem = idx >> 7;
  int b   = rem & 63;
  int t   = rem >> 6;
  float4 v = *(const float4*)(x + ((size_t)b * TT + t) * DD + d4 * 4);
  f16x4 o = {(f16)v.x, (f16)v.y, (f16)v.z, (f16)v.w};
  *(f16x4*)(x16 + ((size_t)t * BB + b) * DD + d4 * 4) = o;
}

// ---- persistent 2-layer LSTM, dataflow + replicated-epoch sync ----
// Contention fix (R10 post-mortem): epochs are broadcast to GRP=32 replica
// cachelines; consumer bid%GRP polls only its replica with s_sleep(EPSLP).
// ~8 pollers/line instead of ~128 on one line -> LLC line service queue
// stays short; epoch store + aggregator flag reads no longer queue behind
// a poll storm.
__global__ __launch_bounds__(512, 2) void lstm_persistent(
    const f16* __restrict__ x16,
    const float* __restrict__ Wih0, const float* __restrict__ Whh0,
    const float* __restrict__ bih0, const float* __restrict__ bhh0,
    const float* __restrict__ Wih1, const float* __restrict__ Whh1,
    const float* __restrict__ bih1, const float* __restrict__ bhh1,
    f16* __restrict__ h0ring, f16* __restrict__ h1ring, int* __restrict__ bar) {
  extern __shared__ f16 lds[];
  const int bid  = blockIdx.x;
  const bool IS1 = (bid >= L0B);
  const int j0   = (IS1 ? bid - L0B : bid) * COLS;
  const int tid  = threadIdx.x;
  const int wv   = tid >> 6;
  const int lane = tid & 63;
  const int wt   = wv >> 2;     // weight tile: 0={i,f}, 1={g,o}
  const int bt   = wv & 3;      // batch tile (16 rows)
  const int col  = lane & 15;
  const int kgrp = lane >> 4;
  const int jc   = col & 7;

  const int CHK = IS1 ? CHK1 : CHK0;
  const int TS  = IS1 ? TS1 : TS0;
  const int DIN = IS1 ? HH : DD;
  f16* Wpk    = lds;
  float* xbuf = (float*)(lds + 2 * TS1);          // [4][16][16] f32
  f16* hbuf   = (f16*)(xbuf + 4 * 16 * 16);       // [4][16][8]

  // ---- prologue: pack weights into MFMA-fragment order (fp32 -> fp16) ----
  {
    const float* Wi = IS1 ? Wih1 : Wih0;
    const float* Wh = IS1 ? Whh1 : Whh0;
    const int grow = (wt * 2 + ((lane & 15) >> 3)) * HH + j0 + (lane & 7);
    const float* rowi = Wi + (size_t)grow * DIN;
    const float* rowh = Wh + (size_t)grow * HH;
    for (int ck = bt; ck < CHK; ck += 4) {
      int k = ck * 32 + kgrp * 8;
      const float* src = (k < DIN) ? (rowi + k) : (rowh + (k - DIN));
      float4 u = *(const float4*)src;
      float4 v = *(const float4*)(src + 4);
      f16x8 w = {(f16)u.x, (f16)u.y, (f16)u.z, (f16)u.w,
                 (f16)v.x, (f16)v.y, (f16)v.z, (f16)v.w};
      *(f16x8*)(Wpk + (size_t)wt * TS + (size_t)ck * 512 + lane * 8) = w;
    }
  }
  const float* bi = IS1 ? bih1 : bih0;
  const float* bh = IS1 ? bhh1 : bhh0;
  const int bg = wt * 2 + (col >> 3);
  const float bias = bi[bg * HH + j0 + jc] + bh[bg * HH + j0 + jc];
  __syncthreads();

  const int arow = bt * 16 + col;
  float creg[4] = {0.f, 0.f, 0.f, 0.f};
  int* flag0 = bar;
  int* flag1 = bar + L0B * 32;
  int* ep0   = bar + 2 * L0B * 32;        // 32 replica lines
  int* ep1   = ep0 + GRP * 32;            // 32 replica lines
  const int myrep = (IS1 ? bid - L0B : bid) & (GRP - 1);
  const f16* bq = Wpk + (size_t)wt * TS + lane * 8;

  // shared epilogue: gate exchange + cell update + sc1 h-store
  auto cellstore = [&](f32x4 acc0, f32x4 acc1, f16* hw) {
    float pv[4];
    #pragma unroll
    for (int r = 0; r < 4; ++r) pv[r] = acc0[r] + acc1[r] + bias;
    if (wt == 1) {
      #pragma unroll
      for (int r = 0; r < 4; ++r) {
        float a = (col < 8) ? FTANH(pv[r]) : FSIG(pv[r]);
        xbuf[((size_t)bt * 16 + kgrp * 4 + r) * 16 + col] = a;
      }
    }
    __syncthreads();
    if (wt == 0) {
      #pragma unroll
      for (int r = 0; r < 4; ++r) {
        float q = __shfl_xor(pv[r], 8);   // partner col+8 holds f-pre
        if (col < 8) {
          float ig = FSIG(pv[r]);
          float fg = FSIG(q);
          const float* xb = xbuf + ((size_t)bt * 16 + kgrp * 4 + r) * 16;
          float gg = xb[jc];
          float og = xb[8 + jc];
          float cc = fg * creg[r] + ig * gg;
          creg[r] = cc;
          hbuf[((size_t)bt * 16 + kgrp * 4 + r) * 8 + jc] = (f16)(og * FTANH(cc));
        }
      }
      if (lane < 16) {
        f16x8 hv = *(const f16x8*)(hbuf + ((size_t)bt * 16 + lane) * 8);
        f16* dst = hw + (size_t)(bt * 16 + lane) * HH + j0;
        i32x4 hvi;
        __builtin_memcpy(&hvi, &hv, 16);
        asm volatile("global_store_dwordx4 %0, %1, off sc1"
                     :: "v"(dst), "v"(hvi) : "memory");
      }
    }
  };

  if (!IS1) {
    // ================= layer 0 =================
    const bool AGG = (bid == 0);
    i32x4 afx[16], afh[32];
    for (int t = 0; t < TT; ++t) {
      // 1. x-loads in flight (no cross-block dep)
      const f16* ax = x16 + ((size_t)t * BB + arow) * DD + kgrp * 8;
      glN<16>(afx, ax);
      // 2. wait peers' h0[t-1]; ring slot free of L1 readers (x flight hides)
      if (AGG) {
        if (tid < L0B)
          while (__hip_atomic_load(flag0 + tid * 32, __ATOMIC_RELAXED, ALOAD) < t)
            __builtin_amdgcn_s_sleep(1);
      } else if (tid == 0) {
        while (__hip_atomic_load(ep0 + myrep * 32, __ATOMIC_RELAXED, ALOAD) < t)
          __builtin_amdgcn_s_sleep(EPSLP);
      }
      if (tid == 256) {
        while (__hip_atomic_load(ep1 + myrep * 32, __ATOMIC_RELAXED, ALOAD) < t - (RING - 1))
          __builtin_amdgcn_s_sleep(EPSLP);
      }
      __syncthreads();
      if (AGG && tid < GRP)
        __hip_atomic_store(ep0 + tid * 32, t, __ATOMIC_RELAXED, ALOAD);
      // 3. h-loads in flight behind x
      const f16* ah = h0ring + (size_t)((t - 1) & (RING - 1)) * HSZ +
                      (size_t)arow * HH + kgrp * 8;
      glN<32>(afh, ah);
      // 4. consume x (vmcnt 40,32), then h (24..0)
      f32x4 acc0 = {0.f, 0.f, 0.f, 0.f};
      f32x4 acc1 = {0.f, 0.f, 0.f, 0.f};
      mfN<16, 32, 0>(afx, bq, acc0, acc1);
      mfN<32, 0, 16>(afh, bq, acc0, acc1);
      cellstore(acc0, acc1, h0ring + (size_t)(t & (RING - 1)) * HSZ);
      asm volatile("s_waitcnt vmcnt(0)" ::: "memory");
      __syncthreads();
      if (tid == 0)
        __hip_atomic_store(flag0 + bid * 32, t + 1, __ATOMIC_RELAXED, ALOAD);
    }
    // final epoch0 pass for L1's last step
    if (AGG) {
      if (tid < L0B)
        while (__hip_atomic_load(flag0 + tid * 32, __ATOMIC_RELAXED, ALOAD) < TT)
          __builtin_amdgcn_s_sleep(1);
      __syncthreads();
      if (tid < GRP)
        __hip_atomic_store(ep0 + tid * 32, TT, __ATOMIC_RELAXED, ALOAD);
    }
  } else {
    // ================= layer 1 =================
    const bool AGG = (bid == L0B);
    i32x4 af[32];
    for (int u = 0; u < TT; ++u) {
      // 1. h0[u] ready? (L0 runs ahead -> nearly always one load)
      if (tid == 0)
        while (__hip_atomic_load(ep0 + myrep * 32, __ATOMIC_RELAXED, ALOAD) < u + 1)
          __builtin_amdgcn_s_sleep(EPSLP);
      __syncthreads();
      // 2. h0 loads in flight
      const f16* h0p = h0ring + (size_t)(u & (RING - 1)) * HSZ +
                       (size_t)arow * HH + kgrp * 8;
      glN<32>(af, h0p);
      // 3. wait peers' h1[u-1] WHILE h0 loads fly
      if (AGG) {
        if (tid < L0B)
          while (__hip_atomic_load(flag1 + tid * 32, __ATOMIC_RELAXED, ALOAD) < u)
            __builtin_amdgcn_s_sleep(1);
      } else if (tid == 0) {
        while (__hip_atomic_load(ep1 + myrep * 32, __ATOMIC_RELAXED, ALOAD) < u)
          __builtin_amdgcn_s_sleep(EPSLP);
      }
      __syncthreads();
      if (AGG && tid < GRP)
        __hip_atomic_store(ep1 + tid * 32, u, __ATOMIC_RELAXED, ALOAD);
      // 4. consume h0 (24..0)
      f32x4 acc0 = {0.f, 0.f, 0.f, 0.f};
      f32x4 acc1 = {0.f, 0.f, 0.f, 0.f};
      mfN<32, 0, 0>(af, bq, acc0, acc1);
      // 5. h1 loads + consume (24..0)
      const f16* h1p = h1ring + (size_t)((u - 1) & (RING - 1)) * HSZ +
                       (size_t)arow * HH + kgrp * 8;
      glN<32>(af, h1p);
      mfN<32, 0, 32>(af, bq, acc0, acc1);
      cellstore(acc0, acc1, h1ring + (size_t)(u & (RING - 1)) * HSZ);
      asm volatile("s_waitcnt vmcnt(0)" ::: "memory");
      __syncthreads();
      if (tid == 0)
        __hip_atomic_store(flag1 + (bid - L0B) * 32, u + 1, __ATOMIC_RELAXED, ALOAD);
    }
  }
}

// ---- FC: logits[b][cls] = b_fc[cls] + sum_k concat(h0,h1)[b][k] * Wfc[cls][k]
__global__ __launch_bounds__(256) void fc_kernel(const f16* __restrict__ h0f,
                                                 const f16* __restrict__ h1f,
                                                 const float* __restrict__ Wfc,
                                                 const float* __restrict__ bfc,
                                                 float* __restrict__ out) {
  __shared__ f16 hl[64][264];
  __shared__ float Wl[4][260];
  const int tid = threadIdx.x;
  const int cl0 = blockIdx.x * 4;
  const int b   = tid >> 2;
  const int cq  = tid & 3;
  float a = 0.f;
  for (int k0 = 0; k0 < 2 * HH; k0 += 256) {
    #pragma unroll
    for (int i = 0; i < 8; i++) {
      int v   = tid + i * 256;
      int row = v >> 5;
      int kk  = (v & 31) * 8;
      int kg  = k0 + kk;
      const f16* src = (kg < HH) ? (h0f + (size_t)row * HH + kg)
                                 : (h1f + (size_t)row * HH + (kg - HH));
      *(f16x8*)(&hl[row][kk]) = *(const f16x8*)src;
    }
    {
      int row = tid >> 6;
      int kk  = (tid & 63) * 4;
      *(float4*)(&Wl[row][kk]) = *(const float4*)(Wfc + (size_t)(cl0 + row) * (2 * HH) + k0 + kk);
    }
    __syncthreads();
    #pragma unroll 8
    for (int k = 0; k < 256; k++) a += (float)hl[b][k] * Wl[cq][k];
    __syncthreads();
  }
  out[(size_t)b * NCLS + cl0 + cq] = a + bfc[cl0 + cq];
}

extern "C" void kernel_launch(void* const* d_in, const int* in_sizes, int n_in,
                              void* d_out, int out_size, void* d_ws, size_t ws_size,
                              hipStream_t stream) {
  const float* x    = (const float*)d_in[0];
  const float* Wih0 = (const float*)d_in[1];
  const float* Whh0 = (const float*)d_in[2];
  const float* bih0 = (const float*)d_in[3];
  const float* bhh0 = (const float*)d_in[4];
  const float* Wih1 = (const float*)d_in[5];
  const float* Whh1 = (const float*)d_in[6];
  const float* bih1 = (const float*)d_in[7];
  const float* bhh1 = (const float*)d_in[8];
  const float* Wfc  = (const float*)d_in[9];
  const float* bfc  = (const float*)d_in[10];
  float* out = (float*)d_out;

  char* p = (char*)d_ws;
  auto alloc = [&](size_t bytes) {
    char* r = p;
    p += (bytes + 255) & ~(size_t)255;
    return r;
  };
  f16* x16    = (f16*)alloc((size_t)BB * TT * DD * 2);
  f16* h0ring = (f16*)alloc((size_t)RING * HSZ * 2);
  f16* h1ring = (f16*)alloc((size_t)RING * HSZ * 2);
  int* bar    = (int*)alloc((size_t)BARWORDS * 4);

  if ((size_t)(p - (char*)d_ws) > ws_size) return;  // ws too small: bail cleanly

  (void)hipMemsetAsync(bar, 0, (size_t)BARWORDS * 4, stream);
  // slot 31 = t=-1 zeros for both rings
  (void)hipMemsetAsync(h0ring + (size_t)(RING - 1) * HSZ, 0, (size_t)HSZ * 2, stream);
  (void)hipMemsetAsync(h1ring + (size_t)(RING - 1) * HSZ, 0, (size_t)HSZ * 2, stream);

  prep_x_kernel<<<dim3(TT * BB * (DD / 4) / 256), dim3(256), 0, stream>>>(x, x16);

  (void)hipFuncSetAttribute((const void*)lstm_persistent,
                            hipFuncAttributeMaxDynamicSharedMemorySize, DYNLDS);
  lstm_persistent<<<dim3(NB), dim3(512), DYNLDS, stream>>>(
      x16, Wih0, Whh0, bih0, bhh0, Wih1, Whh1, bih1, bhh1, h0ring, h1ring, bar);

  // h0[255] -> slot 255&31 = 31; h1[255] -> slot 31
  fc_kernel<<<dim3(NCLS / 4), dim3(256), 0, stream>>>(
      h0ring + (size_t)(RING - 1) * HSZ, h1ring + (size_t)(RING - 1) * HSZ,
      Wfc, bfc, out);
}